// Round 9
// baseline (465.213 us; speedup 1.0000x reference)
//
#include <hip/hip_runtime.h>
#include <hip/hip_bf16.h>
#include <math.h>

#define LEAKY 0.01f
#define SCAN_BLOCK 256
#define SCAN_ITEMS 4
#define SCAN_TILE (SCAN_BLOCK * SCAN_ITEMS)  // 1024 items per block

struct __align__(8) Bf4 { __hip_bfloat16 a, b, c, d; };

__device__ __forceinline__ float bfu(unsigned short u) {
    return __uint_as_float((unsigned)u << 16);
}

__global__ void zero_i32(int* __restrict__ p, int n) {
    int i = blockIdx.x * blockDim.x + threadIdx.x;
    if (i < n) p[i] = 0;
}

// counts degree AND records each edge's rank within its row (kills fill atomic)
__global__ void count_edges(const int* __restrict__ row, int E,
                            int* __restrict__ deg, int* __restrict__ rank) {
    int i = blockIdx.x * blockDim.x + threadIdx.x;
    if (i < E) rank[i] = atomicAdd(&deg[row[i]], 1);
}

// ---- 2-phase device-wide exclusive scan of deg[N] -> row_ptr[N+1] ----
__global__ __launch_bounds__(SCAN_BLOCK) void scan_phase1(
    const int* __restrict__ deg, int* __restrict__ blocksum, int N) {
    __shared__ int red[SCAN_BLOCK];
    int b = blockIdx.x, t = threadIdx.x;
    int base = b * SCAN_TILE + t * SCAN_ITEMS;
    int s = 0;
#pragma unroll
    for (int j = 0; j < SCAN_ITEMS; j++) {
        int i = base + j;
        if (i < N) s += deg[i];
    }
    red[t] = s;
    __syncthreads();
    for (int off = SCAN_BLOCK / 2; off > 0; off >>= 1) {
        if (t < off) red[t] += red[t + off];
        __syncthreads();
    }
    if (t == 0) blocksum[b] = red[0];
}

__global__ __launch_bounds__(SCAN_BLOCK) void scan_phase3(
    const int* __restrict__ deg, const int* __restrict__ blocksum,
    int* __restrict__ row_ptr, int G, int N) {
    __shared__ int bs[SCAN_BLOCK];
    __shared__ int red[SCAN_BLOCK];
    int b = blockIdx.x, t = threadIdx.x;
    bs[t] = (t < G) ? blocksum[t] : 0;
    __syncthreads();
    for (int off = 1; off < SCAN_BLOCK; off <<= 1) {
        int v = (t >= off) ? bs[t - off] : 0;
        __syncthreads();
        bs[t] += v;
        __syncthreads();
    }
    int boff = (b == 0) ? 0 : bs[b - 1];
    if (b == 0 && t == 0) row_ptr[N] = bs[G - 1];

    int base = b * SCAN_TILE + t * SCAN_ITEMS;
    int v[SCAN_ITEMS];
    int s = 0;
#pragma unroll
    for (int j = 0; j < SCAN_ITEMS; j++) {
        int i = base + j;
        v[j] = (i < N) ? deg[i] : 0;
        s += v[j];
    }
    red[t] = s;
    __syncthreads();
    for (int off = 1; off < SCAN_BLOCK; off <<= 1) {
        int x = (t >= off) ? red[t - off] : 0;
        __syncthreads();
        red[t] += x;
        __syncthreads();
    }
    int run = boff + ((t == 0) ? 0 : red[t - 1]);
#pragma unroll
    for (int j = 0; j < SCAN_ITEMS; j++) {
        int i = base + j;
        if (i < N) { row_ptr[i] = run; run += v[j]; }
    }
}
// ----------------------------------------------------------------------

// a0 = concat(user_embed, entity_embed) (fp32) + bf16 gather copy
__global__ void build_a0(const float4* __restrict__ ue, const float4* __restrict__ ee,
                         float4* __restrict__ a0, __hip_bfloat16* __restrict__ a0b,
                         int nu4, int ntot4) {
    int i = blockIdx.x * blockDim.x + threadIdx.x;
    if (i < ntot4) {
        float4 v = (i < nu4) ? ue[i] : ee[i - nu4];
        a0[i] = v;
        Bf4 q = {__float2bfloat16(v.x), __float2bfloat16(v.y),
                 __float2bfloat16(v.z), __float2bfloat16(v.w)};
        *(Bf4*)&a0b[(size_t)i * 4] = q;
    }
}

// atomic-free CSR fill using precomputed ranks
__global__ void fill_csr(const int* __restrict__ row, const int* __restrict__ col,
                         const float* __restrict__ val, const int* __restrict__ rank,
                         const int* __restrict__ row_ptr, int E,
                         int2* __restrict__ csr) {
    int i = blockIdx.x * blockDim.x + threadIdx.x;
    if (i < E) {
        int p = row_ptr[row[i]] + rank[i];
        csr[p] = make_int2(col[i], __float_as_int(val[i]));
    }
}

__device__ __forceinline__ void fma4(float o[4], float sv, const float4& wv) {
    o[0] = fmaf(sv, wv.x, o[0]);
    o[1] = fmaf(sv, wv.y, o[1]);
    o[2] = fmaf(sv, wv.z, o[2]);
    o[3] = fmaf(sv, wv.w, o[3]);
}

// Fused GNN layer, concurrency-maximized.
// Block = 256 thr (4 waves); NPW nodes/wave (4 for DOUT=64, 8 for DOUT=32).
// Phase 1: 4 nodes aggregated INTERLEAVED per round — metadata for all 4
//   loaded upfront (independent), gather sub-chunks of 8 edges round-robin
//   across nodes (~32 scattered 2B/lane loads in flight per wave). lane=dim,
//   no cross-lane fold. Dummy edges (col=0,val=0) hit the hot row-0 line.
// Phase 2: each wave MLPs its OWN nodes from LDS S (reg-blocked, W from
//   global/L1) — no cross-wave sharing, no __syncthreads.
// __launch_bounds__(256,8): VGPR<=64 -> 8 blocks/CU resident (2x prior TLP).
template<int DOUT>
__global__ __launch_bounds__(256, 8) void gnn_layer(
    const float* __restrict__ feats, const __hip_bfloat16* __restrict__ featsb,
    const int2* __restrict__ csr, const int* __restrict__ row_ptr,
    const float* __restrict__ W1, const float* __restrict__ b1,
    const float* __restrict__ W2, const float* __restrict__ b2,
    float* __restrict__ out, __hip_bfloat16* __restrict__ outb, int N) {
    constexpr int NPW = (DOUT == 64) ? 4 : 8;
    constexpr int NPB = NPW * 4;
    __shared__ __align__(16) float S[NPB * 132];
    int wv = threadIdx.x >> 6, lane = threadIdx.x & 63;
    const ushort* fb = (const ushort*)featsb;
    int nb = blockIdx.x * NPB + wv * NPW;

    // ---- phase 1: aggregate NPW nodes, 4 at a time interleaved ----
    for (int r = 0; r < NPW; r += 4) {
        int n0 = nb + r;
        int e0[4], dg[4];
        float acc[4] = {0.f, 0.f, 0.f, 0.f};
#pragma unroll
        for (int i = 0; i < 4; i++) {
            int node = n0 + i;
            if (node < N) { e0[i] = row_ptr[node]; dg[i] = row_ptr[node + 1] - e0[i]; }
            else          { e0[i] = 0; dg[i] = 0; }
        }
        int dmax = max(max(dg[0], dg[1]), max(dg[2], dg[3]));
        for (int done = 0; done < dmax; done += 64) {
            int2 m[4];
#pragma unroll
            for (int i = 0; i < 4; i++) {
                int rem = dg[i] - done;
                m[i] = (lane < rem) ? csr[e0[i] + done + lane] : make_int2(0, 0);
            }
            int cmax = min(dmax - done, 64);
            for (int c = 0; c < cmax; c += 8) {
#pragma unroll
                for (int i = 0; i < 4; i++) {
                    if (c < dg[i] - done) {  // wave-uniform branch
                        float f[8], vv[8];
#pragma unroll
                        for (int u = 0; u < 8; u++) {
                            int col = __shfl(m[i].x, c + u, 64);
                            vv[u] = __int_as_float(__shfl(m[i].y, c + u, 64));
                            f[u] = bfu(fb[(size_t)col * 64 + lane]);
                        }
#pragma unroll
                        for (int u = 0; u < 8; u++) acc[i] = fmaf(vv[u], f[u], acc[i]);
                    }
                }
            }
        }
#pragma unroll
        for (int i = 0; i < 4; i++) {
            int node = n0 + i;
            float x = (node < N) ? feats[(size_t)node * 64 + lane] : 0.f;
            float* sp = &S[(wv * NPW + r + i) * 132];
            sp[lane]      = x + acc[i];  // s1
            sp[64 + lane] = x * acc[i];  // s2
        }
    }
    __threadfence_block();  // wave-local LDS write -> cross-lane read ordering

    // ---- phase 2: MLP + epilogue (wave reads only its own nodes' S) ----
    if constexpr (DOUT == 64) {
        int strip = lane & 15, g = lane >> 4;   // 16 strips x 4 dims; g = node
        int d0 = strip * 4;
        float4 b1v = *(const float4*)&b1[d0];
        float4 b2v = *(const float4*)&b2[d0];
        float o[4] = {b1v.x + b2v.x, b1v.y + b2v.y, b1v.z + b2v.z, b1v.w + b2v.w};
        const float* sp = &S[(wv * 4 + g) * 132];
#pragma unroll
        for (int half = 0; half < 2; half++) {
            const float* W  = half ? W2 : W1;
            const float* sv = sp + half * 64;
#pragma unroll 2
            for (int k = 0; k < 64; k += 4) {
                float4 v   = *(const float4*)&sv[k];
                float4 wr0 = *(const float4*)&W[(k + 0) * 64 + d0];
                float4 wr1 = *(const float4*)&W[(k + 1) * 64 + d0];
                float4 wr2 = *(const float4*)&W[(k + 2) * 64 + d0];
                float4 wr3 = *(const float4*)&W[(k + 3) * 64 + d0];
                fma4(o, v.x, wr0); fma4(o, v.y, wr1);
                fma4(o, v.z, wr2); fma4(o, v.w, wr3);
            }
        }
        float h0 = (o[0] > 0.f) ? o[0] : LEAKY * o[0];
        float h1 = (o[1] > 0.f) ? o[1] : LEAKY * o[1];
        float h2 = (o[2] > 0.f) ? o[2] : LEAKY * o[2];
        float h3 = (o[3] > 0.f) ? o[3] : LEAKY * o[3];
        float ss = h0 * h0 + h1 * h1 + h2 * h2 + h3 * h3;
        ss += __shfl_xor(ss, 1, 64);
        ss += __shfl_xor(ss, 2, 64);
        ss += __shfl_xor(ss, 4, 64);
        ss += __shfl_xor(ss, 8, 64);       // 16 lanes = one node
        float sc = 1.0f / fmaxf(sqrtf(ss), 1e-12f);
        int node = nb + g;
        if (node < N) {
            float4 rv = {h0 * sc, h1 * sc, h2 * sc, h3 * sc};
            *(float4*)&out[(size_t)node * 64 + d0] = rv;
            Bf4 q = {__float2bfloat16(rv.x), __float2bfloat16(rv.y),
                     __float2bfloat16(rv.z), __float2bfloat16(rv.w)};
            *(Bf4*)&outb[(size_t)node * 64 + d0] = q;
        }
    } else {
        int strip = lane & 7, nI = lane >> 3;   // 8 strips x 4 dims; 8 nodes
        int d0 = strip * 4;
        float4 b1v = *(const float4*)&b1[d0];
        float4 b2v = *(const float4*)&b2[d0];
        float o[4] = {b1v.x + b2v.x, b1v.y + b2v.y, b1v.z + b2v.z, b1v.w + b2v.w};
        const float* sp = &S[(wv * 8 + nI) * 132];
#pragma unroll
        for (int half = 0; half < 2; half++) {
            const float* W  = half ? W2 : W1;
            const float* sv = sp + half * 64;
#pragma unroll 2
            for (int k = 0; k < 64; k += 4) {
                float4 v   = *(const float4*)&sv[k];
                float4 wr0 = *(const float4*)&W[(k + 0) * 32 + d0];
                float4 wr1 = *(const float4*)&W[(k + 1) * 32 + d0];
                float4 wr2 = *(const float4*)&W[(k + 2) * 32 + d0];
                float4 wr3 = *(const float4*)&W[(k + 3) * 32 + d0];
                fma4(o, v.x, wr0); fma4(o, v.y, wr1);
                fma4(o, v.z, wr2); fma4(o, v.w, wr3);
            }
        }
        float h0 = (o[0] > 0.f) ? o[0] : LEAKY * o[0];
        float h1 = (o[1] > 0.f) ? o[1] : LEAKY * o[1];
        float h2 = (o[2] > 0.f) ? o[2] : LEAKY * o[2];
        float h3 = (o[3] > 0.f) ? o[3] : LEAKY * o[3];
        float ss = h0 * h0 + h1 * h1 + h2 * h2 + h3 * h3;
        ss += __shfl_xor(ss, 1, 64);
        ss += __shfl_xor(ss, 2, 64);
        ss += __shfl_xor(ss, 4, 64);       // 8 lanes = one node
        float sc = 1.0f / fmaxf(sqrtf(ss), 1e-12f);
        int node = nb + nI;
        if (node < N) {
            float4 rv = {h0 * sc, h1 * sc, h2 * sc, h3 * sc};
            *(float4*)&out[(size_t)node * 32 + d0] = rv;
        }
    }
}

// final = concat(a0, a1, a2); score[b] = dot(final[u], final[NU+i]) over 160 dims
__global__ __launch_bounds__(256) void score_pairs(
    const float* __restrict__ a0, const float* __restrict__ a1,
    const float* __restrict__ a2,
    const int* __restrict__ uid, const int* __restrict__ iid,
    float* __restrict__ out, int B, int NU) {
    int wave = threadIdx.x >> 6, lane = threadIdx.x & 63;
    int p = blockIdx.x * 4 + wave;
    if (p >= B) return;
    int u = uid[p], it = iid[p];
    size_t un = (size_t)u, in = (size_t)(NU + it);
    float s = a0[un * 64 + lane] * a0[in * 64 + lane];
    s = fmaf(a1[un * 64 + lane], a1[in * 64 + lane], s);
    if (lane < 32) s = fmaf(a2[un * 32 + lane], a2[in * 32 + lane], s);
#pragma unroll
    for (int m = 32; m >= 1; m >>= 1) s += __shfl_xor(s, m, 64);
    if (lane == 0) out[p] = s;
}

extern "C" void kernel_launch(void* const* d_in, const int* in_sizes, int n_in,
                              void* d_out, int out_size, void* d_ws, size_t ws_size,
                              hipStream_t stream) {
    const int*   edge_row  = (const int*)d_in[0];
    const int*   edge_col  = (const int*)d_in[1];
    const float* edge_vals = (const float*)d_in[2];
    const float* ue        = (const float*)d_in[3];
    const float* ee        = (const float*)d_in[4];
    const float* W1_0 = (const float*)d_in[5];
    const float* b1_0 = (const float*)d_in[6];
    const float* W2_0 = (const float*)d_in[7];
    const float* b2_0 = (const float*)d_in[8];
    const float* W1_1 = (const float*)d_in[9];
    const float* b1_1 = (const float*)d_in[10];
    const float* W2_1 = (const float*)d_in[11];
    const float* b2_1 = (const float*)d_in[12];
    const int*   uid  = (const int*)d_in[13];
    const int*   iid  = (const int*)d_in[14];
    float* out = (float*)d_out;

    const int E  = in_sizes[0];
    const int NU = in_sizes[3] / 64;
    const int NE = in_sizes[4] / 64;
    const int N  = NU + NE;
    const int B  = in_sizes[13];
    const int G  = (N + SCAN_TILE - 1) / SCAN_TILE;  // must be <= SCAN_BLOCK

    char* ws = (char*)d_ws;
    size_t off = 0;
    auto alloc = [&](size_t bytes) -> char* {
        char* p = ws + off;
        off = (off + bytes + 255) & ~(size_t)255;
        return p;
    };
    int*   deg      = (int*)alloc((size_t)N * 4);
    int*   rank     = (int*)alloc((size_t)E * 4);
    int*   row_ptr  = (int*)alloc((size_t)(N + 1) * 4);
    int*   blocksum = (int*)alloc((size_t)1024 * 4);
    int2*  csr      = (int2*)alloc((size_t)E * 8);
    float* a0       = (float*)alloc((size_t)N * 64 * 4);
    float* a1       = (float*)alloc((size_t)N * 64 * 4);
    float* a2       = (float*)alloc((size_t)N * 32 * 4);
    __hip_bfloat16* a0b = (__hip_bfloat16*)alloc((size_t)N * 64 * 2);
    __hip_bfloat16* a1b = (__hip_bfloat16*)alloc((size_t)N * 64 * 2);
    (void)ws_size; (void)n_in; (void)out_size; (void)NE;

    zero_i32<<<(N + 255) / 256, 256, 0, stream>>>(deg, N);
    count_edges<<<(E + 255) / 256, 256, 0, stream>>>(edge_row, E, deg, rank);
    scan_phase1<<<G, SCAN_BLOCK, 0, stream>>>(deg, blocksum, N);
    scan_phase3<<<G, SCAN_BLOCK, 0, stream>>>(deg, blocksum, row_ptr, G, N);
    fill_csr<<<(E + 255) / 256, 256, 0, stream>>>(edge_row, edge_col, edge_vals,
                                                  rank, row_ptr, E, csr);
    int ntot4 = N * 16, nu4 = NU * 16;
    build_a0<<<(ntot4 + 255) / 256, 256, 0, stream>>>((const float4*)ue, (const float4*)ee,
                                                      (float4*)a0, a0b, nu4, ntot4);
    gnn_layer<64><<<(N + 15) / 16, 256, 0, stream>>>(a0, a0b, csr, row_ptr,
                                                     W1_0, b1_0, W2_0, b2_0, a1, a1b, N);
    gnn_layer<32><<<(N + 31) / 32, 256, 0, stream>>>(a1, a1b, csr, row_ptr,
                                                     W1_1, b1_1, W2_1, b2_1, a2, nullptr, N);
    score_pairs<<<(B + 3) / 4, 256, 0, stream>>>(a0, a1, a2, uid, iid, out, B, NU);
}

// Round 10
// 446.408 us; speedup vs baseline: 1.0421x; 1.0421x over previous
//
#include <hip/hip_runtime.h>
#include <hip/hip_bf16.h>
#include <math.h>

#define LEAKY 0.01f
#define SCAN_BLOCK 256
#define SCAN_ITEMS 4
#define SCAN_TILE (SCAN_BLOCK * SCAN_ITEMS)  // 1024 items per block

struct __align__(8) Bf4 { __hip_bfloat16 a, b, c, d; };

__device__ __forceinline__ float bfu(unsigned short u) {
    return __uint_as_float((unsigned)u << 16);
}

__global__ void zero_i32(int* __restrict__ p, int n) {
    int i = blockIdx.x * blockDim.x + threadIdx.x;
    if (i < n) p[i] = 0;
}

// counts degree AND records each edge's rank within its row (kills fill atomic)
__global__ void count_edges(const int* __restrict__ row, int E,
                            int* __restrict__ deg, int* __restrict__ rank) {
    int i = blockIdx.x * blockDim.x + threadIdx.x;
    if (i < E) rank[i] = atomicAdd(&deg[row[i]], 1);
}

// ---- 2-phase device-wide exclusive scan of deg[N] -> row_ptr[N+1] ----
__global__ __launch_bounds__(SCAN_BLOCK) void scan_phase1(
    const int* __restrict__ deg, int* __restrict__ blocksum, int N) {
    __shared__ int red[SCAN_BLOCK];
    int b = blockIdx.x, t = threadIdx.x;
    int base = b * SCAN_TILE + t * SCAN_ITEMS;
    int s = 0;
#pragma unroll
    for (int j = 0; j < SCAN_ITEMS; j++) {
        int i = base + j;
        if (i < N) s += deg[i];
    }
    red[t] = s;
    __syncthreads();
    for (int off = SCAN_BLOCK / 2; off > 0; off >>= 1) {
        if (t < off) red[t] += red[t + off];
        __syncthreads();
    }
    if (t == 0) blocksum[b] = red[0];
}

__global__ __launch_bounds__(SCAN_BLOCK) void scan_phase3(
    const int* __restrict__ deg, const int* __restrict__ blocksum,
    int* __restrict__ row_ptr, int G, int N) {
    __shared__ int bs[SCAN_BLOCK];
    __shared__ int red[SCAN_BLOCK];
    int b = blockIdx.x, t = threadIdx.x;
    bs[t] = (t < G) ? blocksum[t] : 0;
    __syncthreads();
    for (int off = 1; off < SCAN_BLOCK; off <<= 1) {
        int v = (t >= off) ? bs[t - off] : 0;
        __syncthreads();
        bs[t] += v;
        __syncthreads();
    }
    int boff = (b == 0) ? 0 : bs[b - 1];
    if (b == 0 && t == 0) row_ptr[N] = bs[G - 1];

    int base = b * SCAN_TILE + t * SCAN_ITEMS;
    int v[SCAN_ITEMS];
    int s = 0;
#pragma unroll
    for (int j = 0; j < SCAN_ITEMS; j++) {
        int i = base + j;
        v[j] = (i < N) ? deg[i] : 0;
        s += v[j];
    }
    red[t] = s;
    __syncthreads();
    for (int off = 1; off < SCAN_BLOCK; off <<= 1) {
        int x = (t >= off) ? red[t - off] : 0;
        __syncthreads();
        red[t] += x;
        __syncthreads();
    }
    int run = boff + ((t == 0) ? 0 : red[t - 1]);
#pragma unroll
    for (int j = 0; j < SCAN_ITEMS; j++) {
        int i = base + j;
        if (i < N) { row_ptr[i] = run; run += v[j]; }
    }
}
// ----------------------------------------------------------------------

// a0 = concat(user_embed, entity_embed) (fp32) + bf16 gather copy
__global__ void build_a0(const float4* __restrict__ ue, const float4* __restrict__ ee,
                         float4* __restrict__ a0, __hip_bfloat16* __restrict__ a0b,
                         int nu4, int ntot4) {
    int i = blockIdx.x * blockDim.x + threadIdx.x;
    if (i < ntot4) {
        float4 v = (i < nu4) ? ue[i] : ee[i - nu4];
        a0[i] = v;
        Bf4 q = {__float2bfloat16(v.x), __float2bfloat16(v.y),
                 __float2bfloat16(v.z), __float2bfloat16(v.w)};
        *(Bf4*)&a0b[(size_t)i * 4] = q;
    }
}

// atomic-free CSR fill using precomputed ranks
__global__ void fill_csr(const int* __restrict__ row, const int* __restrict__ col,
                         const float* __restrict__ val, const int* __restrict__ rank,
                         const int* __restrict__ row_ptr, int E,
                         int2* __restrict__ csr) {
    int i = blockIdx.x * blockDim.x + threadIdx.x;
    if (i < E) {
        int p = row_ptr[row[i]] + rank[i];
        csr[p] = make_int2(col[i], __float_as_int(val[i]));
    }
}

__device__ __forceinline__ void fma4(float o[4], float sv, const float4& wv) {
    o[0] = fmaf(sv, wv.x, o[0]);
    o[1] = fmaf(sv, wv.y, o[1]);
    o[2] = fmaf(sv, wv.z, o[2]);
    o[3] = fmaf(sv, wv.w, o[3]);
}

// Fused GNN layer, concurrency-maximized.
// Block = 256 thr (4 waves); NPW nodes/wave (4 for DOUT=64, 8 for DOUT=32).
// Phase 1: 4 nodes interleaved; per 8-edge round, PASS 1 issues all 4x8=32
//   independent bf16 gathers into f[4][8] registers, PASS 2 does shfl+fma.
//   launch_bounds(256,4) (VGPR cap 128) so the allocator can hold all 32
//   loads in flight — R9's (256,8)/VGPR=32 clamp serialized them (146 us).
// Phase 2: each wave MLPs its OWN nodes from LDS S (reg-blocked, W from
//   global/L1) — no cross-wave sharing, no __syncthreads.
template<int DOUT>
__global__ __launch_bounds__(256, 4) void gnn_layer(
    const float* __restrict__ feats, const __hip_bfloat16* __restrict__ featsb,
    const int2* __restrict__ csr, const int* __restrict__ row_ptr,
    const float* __restrict__ W1, const float* __restrict__ b1,
    const float* __restrict__ W2, const float* __restrict__ b2,
    float* __restrict__ out, __hip_bfloat16* __restrict__ outb, int N) {
    constexpr int NPW = (DOUT == 64) ? 4 : 8;
    constexpr int NPB = NPW * 4;
    __shared__ __align__(16) float S[NPB * 132];
    int wv = threadIdx.x >> 6, lane = threadIdx.x & 63;
    const ushort* fb = (const ushort*)featsb;
    int nb = blockIdx.x * NPB + wv * NPW;

    // ---- phase 1: aggregate NPW nodes, 4 at a time interleaved ----
    for (int r = 0; r < NPW; r += 4) {
        int n0 = nb + r;
        int e0[4], dg[4];
        float acc[4] = {0.f, 0.f, 0.f, 0.f};
#pragma unroll
        for (int i = 0; i < 4; i++) {
            int node = n0 + i;
            if (node < N) { e0[i] = row_ptr[node]; dg[i] = row_ptr[node + 1] - e0[i]; }
            else          { e0[i] = 0; dg[i] = 0; }
        }
        int dmax = max(max(dg[0], dg[1]), max(dg[2], dg[3]));
        for (int done = 0; done < dmax; done += 64) {
            int2 m[4];
#pragma unroll
            for (int i = 0; i < 4; i++) {
                int rem = dg[i] - done;
                m[i] = (lane < rem) ? csr[e0[i] + done + lane] : make_int2(0, 0);
            }
            int cmax = min(dmax - done, 64);
            for (int c = 0; c < cmax; c += 8) {
                float f[4][8];
                // PASS 1: 32 independent gathers in flight
#pragma unroll
                for (int i = 0; i < 4; i++) {
                    if (c < dg[i] - done) {  // wave-uniform
#pragma unroll
                        for (int u = 0; u < 8; u++) {
                            int col = __shfl(m[i].x, c + u, 64);
                            f[i][u] = bfu(fb[(size_t)col * 64 + lane]);
                        }
                    }
                }
                // PASS 2: vals + accumulate
#pragma unroll
                for (int i = 0; i < 4; i++) {
                    if (c < dg[i] - done) {
#pragma unroll
                        for (int u = 0; u < 8; u++) {
                            float v = __int_as_float(__shfl(m[i].y, c + u, 64));
                            acc[i] = fmaf(v, f[i][u], acc[i]);
                        }
                    }
                }
            }
        }
#pragma unroll
        for (int i = 0; i < 4; i++) {
            int node = n0 + i;
            float x = (node < N) ? feats[(size_t)node * 64 + lane] : 0.f;
            float* sp = &S[(wv * NPW + r + i) * 132];
            sp[lane]      = x + acc[i];  // s1
            sp[64 + lane] = x * acc[i];  // s2
        }
    }
    __threadfence_block();  // wave-local LDS write -> cross-lane read ordering

    // ---- phase 2: MLP + epilogue (wave reads only its own nodes' S) ----
    if constexpr (DOUT == 64) {
        int strip = lane & 15, g = lane >> 4;   // 16 strips x 4 dims; g = node
        int d0 = strip * 4;
        float4 b1v = *(const float4*)&b1[d0];
        float4 b2v = *(const float4*)&b2[d0];
        float o[4] = {b1v.x + b2v.x, b1v.y + b2v.y, b1v.z + b2v.z, b1v.w + b2v.w};
        const float* sp = &S[(wv * 4 + g) * 132];
#pragma unroll
        for (int half = 0; half < 2; half++) {
            const float* W  = half ? W2 : W1;
            const float* sv = sp + half * 64;
#pragma unroll 2
            for (int k = 0; k < 64; k += 4) {
                float4 v   = *(const float4*)&sv[k];
                float4 wr0 = *(const float4*)&W[(k + 0) * 64 + d0];
                float4 wr1 = *(const float4*)&W[(k + 1) * 64 + d0];
                float4 wr2 = *(const float4*)&W[(k + 2) * 64 + d0];
                float4 wr3 = *(const float4*)&W[(k + 3) * 64 + d0];
                fma4(o, v.x, wr0); fma4(o, v.y, wr1);
                fma4(o, v.z, wr2); fma4(o, v.w, wr3);
            }
        }
        float h0 = (o[0] > 0.f) ? o[0] : LEAKY * o[0];
        float h1 = (o[1] > 0.f) ? o[1] : LEAKY * o[1];
        float h2 = (o[2] > 0.f) ? o[2] : LEAKY * o[2];
        float h3 = (o[3] > 0.f) ? o[3] : LEAKY * o[3];
        float ss = h0 * h0 + h1 * h1 + h2 * h2 + h3 * h3;
        ss += __shfl_xor(ss, 1, 64);
        ss += __shfl_xor(ss, 2, 64);
        ss += __shfl_xor(ss, 4, 64);
        ss += __shfl_xor(ss, 8, 64);       // 16 lanes = one node
        float sc = 1.0f / fmaxf(sqrtf(ss), 1e-12f);
        int node = nb + g;
        if (node < N) {
            float4 rv = {h0 * sc, h1 * sc, h2 * sc, h3 * sc};
            *(float4*)&out[(size_t)node * 64 + d0] = rv;
            Bf4 q = {__float2bfloat16(rv.x), __float2bfloat16(rv.y),
                     __float2bfloat16(rv.z), __float2bfloat16(rv.w)};
            *(Bf4*)&outb[(size_t)node * 64 + d0] = q;
        }
    } else {
        int strip = lane & 7, nI = lane >> 3;   // 8 strips x 4 dims; 8 nodes
        int d0 = strip * 4;
        float4 b1v = *(const float4*)&b1[d0];
        float4 b2v = *(const float4*)&b2[d0];
        float o[4] = {b1v.x + b2v.x, b1v.y + b2v.y, b1v.z + b2v.z, b1v.w + b2v.w};
        const float* sp = &S[(wv * 8 + nI) * 132];
#pragma unroll
        for (int half = 0; half < 2; half++) {
            const float* W  = half ? W2 : W1;
            const float* sv = sp + half * 64;
#pragma unroll 2
            for (int k = 0; k < 64; k += 4) {
                float4 v   = *(const float4*)&sv[k];
                float4 wr0 = *(const float4*)&W[(k + 0) * 32 + d0];
                float4 wr1 = *(const float4*)&W[(k + 1) * 32 + d0];
                float4 wr2 = *(const float4*)&W[(k + 2) * 32 + d0];
                float4 wr3 = *(const float4*)&W[(k + 3) * 32 + d0];
                fma4(o, v.x, wr0); fma4(o, v.y, wr1);
                fma4(o, v.z, wr2); fma4(o, v.w, wr3);
            }
        }
        float h0 = (o[0] > 0.f) ? o[0] : LEAKY * o[0];
        float h1 = (o[1] > 0.f) ? o[1] : LEAKY * o[1];
        float h2 = (o[2] > 0.f) ? o[2] : LEAKY * o[2];
        float h3 = (o[3] > 0.f) ? o[3] : LEAKY * o[3];
        float ss = h0 * h0 + h1 * h1 + h2 * h2 + h3 * h3;
        ss += __shfl_xor(ss, 1, 64);
        ss += __shfl_xor(ss, 2, 64);
        ss += __shfl_xor(ss, 4, 64);       // 8 lanes = one node
        float sc = 1.0f / fmaxf(sqrtf(ss), 1e-12f);
        int node = nb + nI;
        if (node < N) {
            float4 rv = {h0 * sc, h1 * sc, h2 * sc, h3 * sc};
            *(float4*)&out[(size_t)node * 32 + d0] = rv;
        }
    }
}

// final = concat(a0, a1, a2); score[b] = dot(final[u], final[NU+i]) over 160 dims
__global__ __launch_bounds__(256) void score_pairs(
    const float* __restrict__ a0, const float* __restrict__ a1,
    const float* __restrict__ a2,
    const int* __restrict__ uid, const int* __restrict__ iid,
    float* __restrict__ out, int B, int NU) {
    int wave = threadIdx.x >> 6, lane = threadIdx.x & 63;
    int p = blockIdx.x * 4 + wave;
    if (p >= B) return;
    int u = uid[p], it = iid[p];
    size_t un = (size_t)u, in = (size_t)(NU + it);
    float s = a0[un * 64 + lane] * a0[in * 64 + lane];
    s = fmaf(a1[un * 64 + lane], a1[in * 64 + lane], s);
    if (lane < 32) s = fmaf(a2[un * 32 + lane], a2[in * 32 + lane], s);
#pragma unroll
    for (int m = 32; m >= 1; m >>= 1) s += __shfl_xor(s, m, 64);
    if (lane == 0) out[p] = s;
}

extern "C" void kernel_launch(void* const* d_in, const int* in_sizes, int n_in,
                              void* d_out, int out_size, void* d_ws, size_t ws_size,
                              hipStream_t stream) {
    const int*   edge_row  = (const int*)d_in[0];
    const int*   edge_col  = (const int*)d_in[1];
    const float* edge_vals = (const float*)d_in[2];
    const float* ue        = (const float*)d_in[3];
    const float* ee        = (const float*)d_in[4];
    const float* W1_0 = (const float*)d_in[5];
    const float* b1_0 = (const float*)d_in[6];
    const float* W2_0 = (const float*)d_in[7];
    const float* b2_0 = (const float*)d_in[8];
    const float* W1_1 = (const float*)d_in[9];
    const float* b1_1 = (const float*)d_in[10];
    const float* W2_1 = (const float*)d_in[11];
    const float* b2_1 = (const float*)d_in[12];
    const int*   uid  = (const int*)d_in[13];
    const int*   iid  = (const int*)d_in[14];
    float* out = (float*)d_out;

    const int E  = in_sizes[0];
    const int NU = in_sizes[3] / 64;
    const int NE = in_sizes[4] / 64;
    const int N  = NU + NE;
    const int B  = in_sizes[13];
    const int G  = (N + SCAN_TILE - 1) / SCAN_TILE;  // must be <= SCAN_BLOCK

    char* ws = (char*)d_ws;
    size_t off = 0;
    auto alloc = [&](size_t bytes) -> char* {
        char* p = ws + off;
        off = (off + bytes + 255) & ~(size_t)255;
        return p;
    };
    int*   deg      = (int*)alloc((size_t)N * 4);
    int*   rank     = (int*)alloc((size_t)E * 4);
    int*   row_ptr  = (int*)alloc((size_t)(N + 1) * 4);
    int*   blocksum = (int*)alloc((size_t)1024 * 4);
    int2*  csr      = (int2*)alloc((size_t)E * 8);
    float* a0       = (float*)alloc((size_t)N * 64 * 4);
    float* a1       = (float*)alloc((size_t)N * 64 * 4);
    float* a2       = (float*)alloc((size_t)N * 32 * 4);
    __hip_bfloat16* a0b = (__hip_bfloat16*)alloc((size_t)N * 64 * 2);
    __hip_bfloat16* a1b = (__hip_bfloat16*)alloc((size_t)N * 64 * 2);
    (void)ws_size; (void)n_in; (void)out_size; (void)NE;

    zero_i32<<<(N + 255) / 256, 256, 0, stream>>>(deg, N);
    count_edges<<<(E + 255) / 256, 256, 0, stream>>>(edge_row, E, deg, rank);
    scan_phase1<<<G, SCAN_BLOCK, 0, stream>>>(deg, blocksum, N);
    scan_phase3<<<G, SCAN_BLOCK, 0, stream>>>(deg, blocksum, row_ptr, G, N);
    fill_csr<<<(E + 255) / 256, 256, 0, stream>>>(edge_row, edge_col, edge_vals,
                                                  rank, row_ptr, E, csr);
    int ntot4 = N * 16, nu4 = NU * 16;
    build_a0<<<(ntot4 + 255) / 256, 256, 0, stream>>>((const float4*)ue, (const float4*)ee,
                                                      (float4*)a0, a0b, nu4, ntot4);
    gnn_layer<64><<<(N + 15) / 16, 256, 0, stream>>>(a0, a0b, csr, row_ptr,
                                                     W1_0, b1_0, W2_0, b2_0, a1, a1b, N);
    gnn_layer<32><<<(N + 31) / 32, 256, 0, stream>>>(a1, a1b, csr, row_ptr,
                                                     W1_1, b1_1, W2_1, b2_1, a2, nullptr, N);
    score_pairs<<<(B + 3) / 4, 256, 0, stream>>>(a0, a1, a2, uid, iid, out, B, NU);
}